// Round 10
// baseline (245.745 us; speedup 1.0000x reference)
//
#include <hip/hip_runtime.h>
#include <math.h>

#define D_MODEL 512
#define INNER 64
#define HEADS 8
#define BATCH 4
#define SEQ 2048
#define BHN (BATCH*HEADS)                 // 32
#define PER_MAT ((size_t)BHN*SEQ*INNER)   // 4194304 elements

typedef __attribute__((ext_vector_type(8))) short short8;   // 8 bf16 (4 VGPRs)
typedef __attribute__((ext_vector_type(4))) float floatx4;

#if __has_builtin(__builtin_amdgcn_exp2f)
#define EXP2F(x) __builtin_amdgcn_exp2f(x)
#else
#define EXP2F(x) exp2f(x)
#endif

// async global->LDS DMA, 16B/lane. LDS dest = wave-uniform base + lane*16.
#define GLOAD16(g, l)                                                        \
    __builtin_amdgcn_global_load_lds(                                        \
        (const __attribute__((address_space(1))) void*)(g),                  \
        (__attribute__((address_space(3))) void*)(l), 16, 0, 0)

// split fp32 -> bf16 hi (truncate) + bf16 lo (truncate of residual)
__device__ __forceinline__ void split_bf(float f, unsigned short& h, unsigned short& l) {
    unsigned int u = __float_as_uint(f);
    h = (unsigned short)(u >> 16);
    float hf = __uint_as_float(u & 0xffff0000u);
    l = (unsigned short)(__float_as_uint(f - hf) >> 16);
}

__device__ __forceinline__ void split4(const float* f, uint2& ph, uint2& pl) {
    unsigned int h[4], l[4];
#pragma unroll
    for (int j = 0; j < 4; ++j) {
        unsigned short hu, lu;
        split_bf(f[j], hu, lu);
        h[j] = hu; l[j] = lu;
    }
    ph.x = h[0] | (h[1] << 16); ph.y = h[2] | (h[3] << 16);
    pl.x = l[0] | (l[1] << 16); pl.y = l[2] | (l[3] << 16);
}

// ---------------------------------------------------------------------------
// Prep 0: X (8192x512 fp32) -> Xh/Xl bf16, same layout.
// ---------------------------------------------------------------------------
__global__ __launch_bounds__(256) void split_x(const float* __restrict__ X,
                                               unsigned short* __restrict__ Xh,
                                               unsigned short* __restrict__ Xl) {
    size_t base = ((size_t)blockIdx.x * 256 + threadIdx.x) * 8;
    float4 a = *(const float4*)&X[base];
    float4 b = *(const float4*)&X[base + 4];
    uint2 h0, l0, h1, l1;
    split4((const float*)&a, h0, l0);
    split4((const float*)&b, h1, l1);
    *(uint4*)&Xh[base] = make_uint4(h0.x, h0.y, h1.x, h1.y);
    *(uint4*)&Xl[base] = make_uint4(l0.x, l0.y, l1.x, l1.y);
}

// ---------------------------------------------------------------------------
// Prep 1: W (24 mats of 512x64 fp32) -> Wt hi/lo bf16 [n=1536][k=512].
// ---------------------------------------------------------------------------
__global__ __launch_bounds__(256) void split_w(const float* __restrict__ kern,
                                               unsigned short* __restrict__ Wth,
                                               unsigned short* __restrict__ Wtl) {
    __shared__ float tile[64 * 65];
    const int t = threadIdx.x;
    const int mat = blockIdx.x, k0 = blockIdx.y * 64;
#pragma unroll
    for (int c = 0; c < 4; ++c) {
        int idx = t + c * 256;
        int kl = idx >> 4, i4 = idx & 15;
        float4 v = *(const float4*)&kern[((size_t)mat * 512 + k0 + kl) * 64 + i4 * 4];
        tile[(i4 * 4 + 0) * 65 + kl] = v.x;
        tile[(i4 * 4 + 1) * 65 + kl] = v.y;
        tile[(i4 * 4 + 2) * 65 + kl] = v.z;
        tile[(i4 * 4 + 3) * 65 + kl] = v.w;
    }
    __syncthreads();
    {
        int i = t >> 2, kq = t & 3;
        uint2 h0, l0, h1, l1, h2, l2, h3, l3;
        float f[16];
#pragma unroll
        for (int jj = 0; jj < 16; ++jj) f[jj] = tile[i * 65 + kq * 16 + jj];
        split4(f, h0, l0); split4(f + 4, h1, l1);
        split4(f + 8, h2, l2); split4(f + 12, h3, l3);
        size_t off = ((size_t)mat * 64 + i) * 512 + k0 + kq * 16;
        *(uint4*)&Wth[off]     = make_uint4(h0.x, h0.y, h1.x, h1.y);
        *(uint4*)&Wth[off + 8] = make_uint4(h2.x, h2.y, h3.x, h3.y);
        *(uint4*)&Wtl[off]     = make_uint4(l0.x, l0.y, l1.x, l1.y);
        *(uint4*)&Wtl[off + 8] = make_uint4(l2.x, l2.y, l3.x, l3.y);
    }
}

// ---------------------------------------------------------------------------
// Prep 2: HK (512x512 fp32) -> HKt hi/lo bf16 [n=512][k=512] (transpose).
// ---------------------------------------------------------------------------
__global__ __launch_bounds__(256) void split_hk(const float* __restrict__ HK,
                                                unsigned short* __restrict__ Hth,
                                                unsigned short* __restrict__ Htl) {
    __shared__ float tile[64 * 65];
    const int t = threadIdx.x;
    const int n0 = blockIdx.x * 64, k0 = blockIdx.y * 64;
#pragma unroll
    for (int c = 0; c < 4; ++c) {
        int idx = t + c * 256;
        int kl = idx >> 4, n4 = idx & 15;
        float4 v = *(const float4*)&HK[(size_t)(k0 + kl) * 512 + n0 + n4 * 4];
        tile[(n4 * 4 + 0) * 65 + kl] = v.x;
        tile[(n4 * 4 + 1) * 65 + kl] = v.y;
        tile[(n4 * 4 + 2) * 65 + kl] = v.z;
        tile[(n4 * 4 + 3) * 65 + kl] = v.w;
    }
    __syncthreads();
    {
        int i = t >> 2, kq = t & 3;
        uint2 h0, l0, h1, l1, h2, l2, h3, l3;
        float f[16];
#pragma unroll
        for (int jj = 0; jj < 16; ++jj) f[jj] = tile[i * 65 + kq * 16 + jj];
        split4(f, h0, l0); split4(f + 4, h1, l1);
        split4(f + 8, h2, l2); split4(f + 12, h3, l3);
        size_t off = (size_t)(n0 + i) * 512 + k0 + kq * 16;
        *(uint4*)&Hth[off]     = make_uint4(h0.x, h0.y, h1.x, h1.y);
        *(uint4*)&Hth[off + 8] = make_uint4(h2.x, h2.y, h3.x, h3.y);
        *(uint4*)&Htl[off]     = make_uint4(l0.x, l0.y, l1.x, l1.y);
        *(uint4*)&Htl[off + 8] = make_uint4(l2.x, l2.y, l3.x, l3.y);
    }
}

// ---------------------------------------------------------------------------
// Kernel 1: QKV projection, split-bf16 MFMA.
// R17: staging via __builtin_amdgcn_global_load_lds width=16 (async DMA,
// no VGPR round-trip). LDS dest layout is linear in thread id (dst = idx*16B)
// so the wave-uniform-base + lane*16 constraint holds exactly. Barriers and
// everything else unchanged (R14-verified: waves_per_eu(3,3), 3 blocks/CU,
// whole 768-block grid in one round).
// ---------------------------------------------------------------------------
__global__ __launch_bounds__(256) __attribute__((amdgpu_waves_per_eu(3, 3)))
void qkv_mfma(const unsigned short* __restrict__ Xh,
              const unsigned short* __restrict__ Xl,
              const unsigned short* __restrict__ Wth,
              const unsigned short* __restrict__ Wtl,
              unsigned short* __restrict__ Qh,
              unsigned short* __restrict__ Ql,
              unsigned short* __restrict__ Kh,
              unsigned short* __restrict__ Kl,
              unsigned short* __restrict__ Vth,
              unsigned short* __restrict__ Vtl) {
    __shared__ __align__(16) unsigned short smem[16384];   // 32 KB
    unsigned short* Ah = smem;            // [m][k] 128x32
    unsigned short* Al = smem + 4096;
    unsigned short* Bh = smem + 8192;     // [n][k] 128x32
    unsigned short* Bl = smem + 12288;

    const int t = threadIdx.x;
    const int w = t >> 6, lane = t & 63;
    const int quad = lane >> 4, l16 = lane & 15;
    const int wm = w & 1, wn = w >> 1;
    const int r0 = blockIdx.x * 128, n0 = blockIdx.y * 128;
    const int wub = (t & ~63);            // wave-uniform thread base

    floatx4 acc[4][4];
#pragma unroll
    for (int mt = 0; mt < 4; ++mt)
#pragma unroll
        for (int nt = 0; nt < 4; ++nt) acc[mt][nt] = (floatx4)(0.f);

    for (int ko = 0; ko < 16; ++ko) {
        const int k0 = ko * 32;
        __syncthreads();
        // A-tile: idx = t + c*256 -> LDS offset idx*16B (linear in t ✓)
#pragma unroll
        for (int c = 0; c < 2; ++c) {
            int idx = t + c * 256;
            int row = idx >> 2, part = idx & 3;
            size_t src = (size_t)(r0 + row) * 512 + k0 + part * 8;
            unsigned short* lbase = Ah + (size_t)(c * 256 + wub) * 8;
            GLOAD16(&Xh[src], lbase);
            GLOAD16(&Xl[src], lbase + 4096);
        }
        // B-tile
#pragma unroll
        for (int c = 0; c < 2; ++c) {
            int idx = t + c * 256;
            int n = idx >> 2, part = idx & 3;
            size_t src = (size_t)(n0 + n) * 512 + k0 + part * 8;
            unsigned short* lbase = Bh + (size_t)(c * 256 + wub) * 8;
            GLOAD16(&Wth[src], lbase);
            GLOAD16(&Wtl[src], lbase + 4096);
        }
        __syncthreads();   // compiler drains vmcnt before s_barrier

        short8 af[4], alf[4], bf[4], blf[4];
#pragma unroll
        for (int mt = 0; mt < 4; ++mt) {
            af[mt]  = *(const short8*)&Ah[(wm * 64 + mt * 16 + l16) * 32 + quad * 8];
            alf[mt] = *(const short8*)&Al[(wm * 64 + mt * 16 + l16) * 32 + quad * 8];
        }
#pragma unroll
        for (int nt = 0; nt < 4; ++nt) {
            bf[nt]  = *(const short8*)&Bh[(wn * 64 + nt * 16 + l16) * 32 + quad * 8];
            blf[nt] = *(const short8*)&Bl[(wn * 64 + nt * 16 + l16) * 32 + quad * 8];
        }
#pragma unroll
        for (int mt = 0; mt < 4; ++mt)
#pragma unroll
            for (int nt = 0; nt < 4; ++nt) {
                acc[mt][nt] = __builtin_amdgcn_mfma_f32_16x16x32_bf16(af[mt], bf[nt], acc[mt][nt], 0, 0, 0);
                acc[mt][nt] = __builtin_amdgcn_mfma_f32_16x16x32_bf16(af[mt], blf[nt], acc[mt][nt], 0, 0, 0);
                acc[mt][nt] = __builtin_amdgcn_mfma_f32_16x16x32_bf16(alf[mt], bf[nt], acc[mt][nt], 0, 0, 0);
            }
    }

    // Epilogue: wave-uniform mat, LDS repack, coalesced stores. Fully
    // unrolled (static acc indexing).
    __syncthreads();
    const int mat = (n0 + wn * 64) >> 6;
    const int h = mat / 3, j = mat - 3 * h;
    const size_t bh = (size_t)(r0 >> 11) * HEADS + h;
    float* pw = (float*)smem + w * 1088;    // 16 x 68 fp32 per wave
    // Q scale = (1/8) * log2(e): attn works in log2 domain -> exp2 = bare v_exp_f32
    const float scale = (j == 0) ? 0.18033688011112042f : 1.0f;

#pragma unroll
    for (int mt = 0; mt < 4; ++mt) {
        asm volatile("" ::: "memory");
#pragma unroll
        for (int nt = 0; nt < 4; ++nt)
#pragma unroll
            for (int r = 0; r < 4; ++r)
                pw[(quad * 4 + r) * 68 + nt * 16 + l16] = acc[mt][nt][r] * scale;
        asm volatile("s_waitcnt lgkmcnt(0)" ::: "memory");
        const int sbase = (r0 & 2047) + wm * 64 + mt * 16;
        if (j < 2) {
            unsigned short* dh = (j == 0) ? Qh : Kh;
            unsigned short* dl = (j == 0) ? Ql : Kl;
            float f[16];
            const float* pr = pw + l16 * 68 + quad * 16;
#pragma unroll
            for (int jj = 0; jj < 16; ++jj) f[jj] = pr[jj];
            uint2 h0, l0, h1, l1, h2, l2, h3, l3;
            split4(f, h0, l0); split4(f + 4, h1, l1);
            split4(f + 8, h2, l2); split4(f + 12, h3, l3);
            size_t off = (bh * SEQ + sbase + l16) * 64 + quad * 16;
            *(uint4*)&dh[off]     = make_uint4(h0.x, h0.y, h1.x, h1.y);
            *(uint4*)&dh[off + 8] = make_uint4(h2.x, h2.y, h3.x, h3.y);
            *(uint4*)&dl[off]     = make_uint4(l0.x, l0.y, l1.x, l1.y);
            *(uint4*)&dl[off + 8] = make_uint4(l2.x, l2.y, l3.x, l3.y);
        } else {
            float f[16];
#pragma unroll
            for (int ss = 0; ss < 16; ++ss) f[ss] = pw[ss * 68 + lane];
            uint2 h0, l0, h1, l1, h2, l2, h3, l3;
            split4(f, h0, l0); split4(f + 4, h1, l1);
            split4(f + 8, h2, l2); split4(f + 12, h3, l3);
            // permuted key layout within each 32-key block:
            //   key (16a + 4g + c) -> pos (8g + 4a + c);  f[4g+c] = key sbase+4g+c
            size_t bb = (bh * 64 + lane) * SEQ + (size_t)(sbase & ~31);
            const int a4 = (sbase & 16) ? 4 : 0;
            *(uint2*)&Vth[bb + a4]      = h0;
            *(uint2*)&Vth[bb + 8 + a4]  = h1;
            *(uint2*)&Vth[bb + 16 + a4] = h2;
            *(uint2*)&Vth[bb + 24 + a4] = h3;
            *(uint2*)&Vtl[bb + a4]      = l0;
            *(uint2*)&Vtl[bb + 8 + a4]  = l1;
            *(uint2*)&Vtl[bb + 16 + a4] = l2;
            *(uint2*)&Vtl[bb + 24 + a4] = l3;
        }
    }
}

// ---------------------------------------------------------------------------
// Kernel 2: flash attention — R16-verified (112 µs, MfmaUtil 40, spill-free).
// 512-thread blocks, 8 waves x 16 q, grid (32,16), waves_per_eu(4,4);
// in-register PV via key-permuted V, log2 softmax, defer-max THR=8.
// UNCHANGED this round.
// ---------------------------------------------------------------------------
__global__ __launch_bounds__(512) __attribute__((amdgpu_waves_per_eu(4, 4)))
void attn_mfma(
        const unsigned short* __restrict__ Qh_g, const unsigned short* __restrict__ Ql_g,
        const unsigned short* __restrict__ Kh_g, const unsigned short* __restrict__ Kl_g,
        const unsigned short* __restrict__ Vth_g, const unsigned short* __restrict__ Vtl_g,
        unsigned short* __restrict__ Oh_g, unsigned short* __restrict__ Ol_g) {
    __shared__ __align__(16) unsigned short smem[4 * 4608];   // 36,864 B
    unsigned short* Ksh = smem;                // [key][dim] 64x72
    unsigned short* Ksl = smem + 4608;
    unsigned short* Vsh = smem + 2 * 4608;     // [dim][pos] 64x72 (pos = permuted key)
    unsigned short* Vsl = smem + 3 * 4608;

    const int t = threadIdx.x;
    const int w = t >> 6, lane = t & 63;
    const int quad = lane >> 4, l16 = lane & 15;
    const int bh = blockIdx.x;
    const int qbase = blockIdx.y * 128 + w * 16;   // 16 queries per wave

    short8 qhf[2], qlf[2];
    {
        const unsigned short* p = Qh_g + ((size_t)bh * SEQ + qbase + l16) * INNER + quad * 8;
        qhf[0] = *(const short8*)p;
        qhf[1] = *(const short8*)(p + 32);
        const unsigned short* p2 = Ql_g + ((size_t)bh * SEQ + qbase + l16) * INNER + quad * 8;
        qlf[0] = *(const short8*)p2;
        qlf[1] = *(const short8*)(p2 + 32);
    }

    floatx4 o[4];
#pragma unroll
    for (int nt = 0; nt < 4; ++nt) o[nt] = (floatx4)(0.f);
    float mrun = -1e30f;
    float lrun = 0.f;

    const uint4* ksrc_h = (const uint4*)(Kh_g + (size_t)bh * SEQ * INNER);
    const uint4* ksrc_l = (const uint4*)(Kl_g + (size_t)bh * SEQ * INNER);
    const uint4* vsrc_h = (const uint4*)(Vth_g + (size_t)bh * INNER * SEQ);
    const uint4* vsrc_l = (const uint4*)(Vtl_g + (size_t)bh * INNER * SEQ);

    // staging geometry: 512 threads stage 512 uint4 per array (one each)
    const int srow = t >> 3, spart = t & 7;
    const int sdst = srow * 72 + spart * 8;

    // prefetch tile 0 into registers (one uint4 per array per thread)
    uint4 pkh, pkl, pvh, pvl;
    pkh = ksrc_h[t];
    pkl = ksrc_l[t];
    pvh = vsrc_h[srow * 256 + spart];
    pvl = vsrc_l[srow * 256 + spart];

    for (int kt = 0; kt < 32; ++kt) {
        __syncthreads();   // (A) prior tile's readers done; drains prefetch
        *(uint4*)&Ksh[sdst] = pkh;
        *(uint4*)&Ksl[sdst] = pkl;
        *(uint4*)&Vsh[sdst] = pvh;
        *(uint4*)&Vsl[sdst] = pvl;
        __syncthreads();   // (B) staging visible

        // ---- S^T: 4 subtiles of 16 keys (S in log2 units) ----
        floatx4 s[4];
        __builtin_amdgcn_s_setprio(1);
#pragma unroll
        for (int st = 0; st < 4; ++st) {
            const unsigned short* ka = &Ksh[(st * 16 + l16) * 72 + quad * 8];
            const unsigned short* kb = &Ksl[(st * 16 + l16) * 72 + quad * 8];
            short8 kh0 = *(const short8*)ka;
            short8 kh1 = *(const short8*)(ka + 32);
            short8 kl0 = *(const short8*)kb;
            short8 kl1 = *(const short8*)(kb + 32);
            floatx4 a = (floatx4)(0.f);
            a = __builtin_amdgcn_mfma_f32_16x16x32_bf16(kh0, qhf[0], a, 0, 0, 0);
            a = __builtin_amdgcn_mfma_f32_16x16x32_bf16(kh1, qhf[1], a, 0, 0, 0);
            a = __builtin_amdgcn_mfma_f32_16x16x32_bf16(kl0, qhf[0], a, 0, 0, 0);
            a = __builtin_amdgcn_mfma_f32_16x16x32_bf16(kl1, qhf[1], a, 0, 0, 0);
            a = __builtin_amdgcn_mfma_f32_16x16x32_bf16(kh0, qlf[0], a, 0, 0, 0);
            a = __builtin_amdgcn_mfma_f32_16x16x32_bf16(kh1, qlf[1], a, 0, 0, 0);
            s[st] = a;
        }
        __builtin_amdgcn_s_setprio(0);

        // ---- prefetch next tile (regs dead during QK^T; fly under PV) ----
        if (kt + 1 < 32) {
            pkh = ksrc_h[(kt + 1) * 512 + t];
            pkl = ksrc_l[(kt + 1) * 512 + t];
            pvh = vsrc_h[srow * 256 + (kt + 1) * 8 + spart];
            pvl = vsrc_l[srow * 256 + (kt + 1) * 8 + spart];
        }

        // ---- online softmax (log2 domain), defer-max THR=8 ----
        {
            float mloc = s[0][0];
#pragma unroll
            for (int st = 0; st < 4; ++st)
#pragma unroll
                for (int r = 0; r < 4; ++r) mloc = fmaxf(mloc, s[st][r]);
            mloc = fmaxf(mloc, __shfl_xor(mloc, 16));
            mloc = fmaxf(mloc, __shfl_xor(mloc, 32));
            if (!__all(mloc - mrun <= 8.f)) {
                float mn = fmaxf(mrun, mloc);
                float alpha = EXP2F(mrun - mn);
                mrun = mn;
                lrun *= alpha;
#pragma unroll
                for (int nt = 0; nt < 4; ++nt) o[nt] = o[nt] * alpha;
            }
            float rs = 0.f;
#pragma unroll
            for (int st = 0; st < 4; ++st)
#pragma unroll
                for (int r = 0; r < 4; ++r) {
                    float p = EXP2F(s[st][r] - mrun);
                    s[st][r] = p;
                    rs += p;
                }
            rs += __shfl_xor(rs, 16);
            rs += __shfl_xor(rs, 32);
            lrun += rs;
        }

        // ---- PV: P stays in registers.
        // B-operand slot (quad, j) wants key 32*half + 8*quad + j under the
        // permuted-V order, which equals s[2*half + (j>>2)][j&3] exactly. ----
#pragma unroll
        for (int half = 0; half < 2; ++half) {
            short8 phf, plf;
#pragma unroll
            for (int j = 0; j < 8; ++j) {
                unsigned short hu, lu;
                split_bf(s[2 * half + (j >> 2)][j & 3], hu, lu);
                phf[j] = (short)hu;
                plf[j] = (short)lu;
            }
            __builtin_amdgcn_s_setprio(1);
#pragma unroll
            for (int nt = 0; nt < 4; ++nt) {
                const unsigned short* va = &Vsh[(nt * 16 + l16) * 72 + half * 32 + quad * 8];
                const unsigned short* vb = &Vsl[(nt * 16 + l16) * 72 + half * 32 + quad * 8];
                short8 vh = *(const short8*)va;
                short8 vl = *(const short8*)vb;
                o[nt] = __builtin_amdgcn_mfma_f32_16x16x32_bf16(vh, phf, o[nt], 0, 0, 0);
                o[nt] = __builtin_amdgcn_mfma_f32_16x16x32_bf16(vh, plf, o[nt], 0, 0, 0);
                o[nt] = __builtin_amdgcn_mfma_f32_16x16x32_bf16(vl, phf, o[nt], 0, 0, 0);
            }
            __builtin_amdgcn_s_setprio(0);
        }
    }

    // ---- epilogue: repack O via LDS -> full-line coalesced uint4 stores.
    // Per-wave disjoint regions: 8 x 1088 fp32 = 34.8 KB within dead K/V smem.
    __syncthreads();   // all waves done reading K/V LDS; safe to reuse as scratch
    {
        const float inv = 1.f / lrun;
        float* pq = (float*)smem + w * 1088;
#pragma unroll
        for (int nt = 0; nt < 4; ++nt) {
            float4 v = make_float4(o[nt][0] * inv, o[nt][1] * inv,
                                   o[nt][2] * inv, o[nt][3] * inv);
            *(float4*)&pq[l16 * 68 + nt * 16 + quad * 4] = v;
        }
        asm volatile("s_waitcnt lgkmcnt(0)" ::: "memory");
        const float* pr = pq + l16 * 68 + quad * 16;
        float f[16];
#pragma unroll
        for (int jj = 0; jj < 16; ++jj) f[jj] = pr[jj];
        uint2 h0, l0, h1, l1, h2, l2, h3, l3;
        split4(f, h0, l0); split4(f + 4, h1, l1);
        split4(f + 8, h2, l2); split4(f + 12, h3, l3);
        size_t off = ((size_t)bh * SEQ + qbase + l16) * 64 + quad * 16;
        *(uint4*)&Oh_g[off]     = make_uint4(h0.x, h0.y, h1.x, h1.y);
        *(uint4*)&Oh_g[off + 8] = make_uint4(h2.x, h2.y, h3.x, h3.y);
        *(uint4*)&Ol_g[off]     = make_uint4(l0.x, l0.y, l1.x, l1.y);
        *(uint4*)&Ol_g[off + 8] = make_uint4(l2.x, l2.y, l3.x, l3.y);
    }
}

// ---------------------------------------------------------------------------
// Kernel 3: output projection, split-bf16 MFMA. 64x128 tiles, grid (128,4)
// = 512 blocks = 2 blocks/CU; waves_per_eu(2,2) (R14-verified).
// R17: staging via global_load_lds width=16 (dest layouts linear in t ✓).
// ---------------------------------------------------------------------------
__global__ __launch_bounds__(256) __attribute__((amdgpu_waves_per_eu(2, 2)))
void out_proj_mfma(const unsigned short* __restrict__ Oh,
                   const unsigned short* __restrict__ Ol,
                   const unsigned short* __restrict__ Hth,
                   const unsigned short* __restrict__ Htl,
                   float* __restrict__ Y) {
    __shared__ __align__(16) unsigned short smem[12288];   // 24.6 KB
    unsigned short* Ah = smem;            // 64 x 32
    unsigned short* Al = smem + 2048;
    unsigned short* Bh = smem + 4096;     // 128 x 32
    unsigned short* Bl = smem + 8192;

    const int t = threadIdx.x;
    const int w = t >> 6, lane = t & 63;
    const int quad = lane >> 4, l16 = lane & 15;
    const int wm = w & 1, wn = w >> 1;
    const int r0 = blockIdx.x * 64, n0 = blockIdx.y * 128;
    const int b = r0 >> 11;
    const int wub = (t & ~63);

    floatx4 acc[2][4];
#pragma unroll
    for (int mt = 0; mt < 2; ++mt)
#pragma unroll
        for (int nt = 0; nt < 4; ++nt) acc[mt][nt] = (floatx4)(0.f);

    for (int ko = 0; ko < 16; ++ko) {
        const int h = ko >> 1, d0 = (ko & 1) * 32;
        const size_t bh = (size_t)b * HEADS + h;
        const int k0 = ko * 32;
        __syncthreads();
        {
            int row = t >> 2, part = t & 3;   // dst = t*16B (linear ✓)
            size_t src = (bh * SEQ + (r0 & 2047) + row) * 64 + d0 + part * 8;
            unsigned short* lbase = Ah + (size_t)wub * 8;
            GLOAD16(&Oh[src], lbase);
            GLOAD16(&Ol[src], lbase + 2048);
        }
#pragma unroll
        for (int c = 0; c < 2; ++c) {
            int idx = t + c * 256;            // dst = idx*16B (linear ✓)
            int n = idx >> 2, part = idx & 3;
            size_t src = (size_t)(n0 + n) * 512 + k0 + part * 8;
            unsigned short* lbase = Bh + (size_t)(c * 256 + wub) * 8;
            GLOAD16(&Hth[src], lbase);
            GLOAD16(&Htl[src], lbase + 4096);
        }
        __syncthreads();

        short8 af[2], alf[2], bf[4], blf[4];
#pragma unroll
        for (int mt = 0; mt < 2; ++mt) {
            af[mt]  = *(const short8*)&Ah[(wm * 32 + mt * 16 + l16) * 32 + quad * 8];
            alf[mt] = *(const short8*)&Al[(wm * 32 + mt * 16 + l16) * 32 + quad * 8];
        }
#pragma unroll
        for (int nt = 0; nt < 4; ++nt) {
            bf[nt]  = *(const short8*)&Bh[(wn * 64 + nt * 16 + l16) * 32 + quad * 8];
            blf[nt] = *(const short8*)&Bl[(wn * 64 + nt * 16 + l16) * 32 + quad * 8];
        }
#pragma unroll
        for (int mt = 0; mt < 2; ++mt)
#pragma unroll
            for (int nt = 0; nt < 4; ++nt) {
                acc[mt][nt] = __builtin_amdgcn_mfma_f32_16x16x32_bf16(af[mt], bf[nt], acc[mt][nt], 0, 0, 0);
                acc[mt][nt] = __builtin_amdgcn_mfma_f32_16x16x32_bf16(af[mt], blf[nt], acc[mt][nt], 0, 0, 0);
                acc[mt][nt] = __builtin_amdgcn_mfma_f32_16x16x32_bf16(alf[mt], bf[nt], acc[mt][nt], 0, 0, 0);
            }
    }

#pragma unroll
    for (int mt = 0; mt < 2; ++mt)
#pragma unroll
        for (int nt = 0; nt < 4; ++nt)
#pragma unroll
            for (int r = 0; r < 4; ++r)
                Y[(size_t)(r0 + wm * 32 + mt * 16 + quad * 4 + r) * 512 +
                  n0 + wn * 64 + nt * 16 + l16] = acc[mt][nt][r];
}

extern "C" void kernel_launch(void* const* d_in, const int* in_sizes, int n_in,
                              void* d_out, int out_size, void* d_ws, size_t ws_size,
                              hipStream_t stream) {
    const float* x    = (const float*)d_in[0];
    const float* kern = (const float*)d_in[1];
    const float* hk   = (const float*)d_in[2];
    float* y = (float*)d_out;

    unsigned short* Qh  = (unsigned short*)d_ws;
    unsigned short* Ql  = Qh + PER_MAT;
    unsigned short* Kh  = Qh + 2 * PER_MAT;
    unsigned short* Kl  = Qh + 3 * PER_MAT;
    unsigned short* Vth = Qh + 4 * PER_MAT;
    unsigned short* Vtl = Qh + 5 * PER_MAT;
    // Xh/Xl alias Oh/Ol: X is dead by the time attn writes O (stream order)
    unsigned short* Oh  = Qh + 6 * PER_MAT;
    unsigned short* Ol  = Qh + 7 * PER_MAT;
    unsigned short* Xh  = Oh;
    unsigned short* Xl  = Ol;
    unsigned short* Wth = Qh + 8 * PER_MAT;
    unsigned short* Wtl = Wth + (size_t)1536 * 512;
    unsigned short* Hth = Wtl + (size_t)1536 * 512;
    unsigned short* Htl = Hth + (size_t)512 * 512;

    split_x<<<dim3(2048), 256, 0, stream>>>(x, Xh, Xl);
    split_w<<<dim3(24, 8), 256, 0, stream>>>(kern, Wth, Wtl);
    split_hk<<<dim3(8, 8), 256, 0, stream>>>(hk, Hth, Htl);
    qkv_mfma<<<dim3(64, 12), 256, 0, stream>>>(Xh, Xl, Wth, Wtl, Qh, Ql, Kh, Kl, Vth, Vtl);
    attn_mfma<<<dim3(32, 16), 512, 0, stream>>>(Qh, Ql, Kh, Kl, Vth, Vtl, Oh, Ol);
    out_proj_mfma<<<dim3(128, 4), 256, 0, stream>>>(Oh, Ol, Hth, Htl, y);
}

// Round 11
// 241.918 us; speedup vs baseline: 1.0158x; 1.0158x over previous
//
#include <hip/hip_runtime.h>
#include <math.h>

#define D_MODEL 512
#define INNER 64
#define HEADS 8
#define BATCH 4
#define SEQ 2048
#define BHN (BATCH*HEADS)                 // 32
#define PER_MAT ((size_t)BHN*SEQ*INNER)   // 4194304 elements

typedef __attribute__((ext_vector_type(8))) short short8;   // 8 bf16 (4 VGPRs)
typedef __attribute__((ext_vector_type(4))) float floatx4;

#if __has_builtin(__builtin_amdgcn_exp2f)
#define EXP2F(x) __builtin_amdgcn_exp2f(x)
#else
#define EXP2F(x) exp2f(x)
#endif

// split fp32 -> bf16 hi (truncate) + bf16 lo (truncate of residual)
__device__ __forceinline__ void split_bf(float f, unsigned short& h, unsigned short& l) {
    unsigned int u = __float_as_uint(f);
    h = (unsigned short)(u >> 16);
    float hf = __uint_as_float(u & 0xffff0000u);
    l = (unsigned short)(__float_as_uint(f - hf) >> 16);
}

__device__ __forceinline__ void split4(const float* f, uint2& ph, uint2& pl) {
    unsigned int h[4], l[4];
#pragma unroll
    for (int j = 0; j < 4; ++j) {
        unsigned short hu, lu;
        split_bf(f[j], hu, lu);
        h[j] = hu; l[j] = lu;
    }
    ph.x = h[0] | (h[1] << 16); ph.y = h[2] | (h[3] << 16);
    pl.x = l[0] | (l[1] << 16); pl.y = l[2] | (l[3] << 16);
}

// ---------------------------------------------------------------------------
// R18: single merged prep kernel. Blocks [0,2048): X split; [2048,2240):
// W split (mat = idx>>3, k0 = (idx&7)*64); [2240,2304): HK split-transpose.
// Identical per-path code to the three R16 prep kernels; merging hides the
// tiny 192/64-block dispatches inside the 2048-block one and removes two
// launch gaps.
// ---------------------------------------------------------------------------
__global__ __launch_bounds__(256) void split_all(const float* __restrict__ X,
                                                 unsigned short* __restrict__ Xh,
                                                 unsigned short* __restrict__ Xl,
                                                 const float* __restrict__ kern,
                                                 unsigned short* __restrict__ Wth,
                                                 unsigned short* __restrict__ Wtl,
                                                 const float* __restrict__ HK,
                                                 unsigned short* __restrict__ Hth,
                                                 unsigned short* __restrict__ Htl) {
    __shared__ float tile[64 * 65];
    const int t = threadIdx.x;
    const int bid = blockIdx.x;

    if (bid < 2048) {
        // ---- X (8192x512 fp32) -> Xh/Xl bf16, same layout ----
        size_t base = ((size_t)bid * 256 + t) * 8;
        float4 a = *(const float4*)&X[base];
        float4 b = *(const float4*)&X[base + 4];
        uint2 h0, l0, h1, l1;
        split4((const float*)&a, h0, l0);
        split4((const float*)&b, h1, l1);
        *(uint4*)&Xh[base] = make_uint4(h0.x, h0.y, h1.x, h1.y);
        *(uint4*)&Xl[base] = make_uint4(l0.x, l0.y, l1.x, l1.y);
        return;
    }

    if (bid < 2048 + 192) {
        // ---- W (24 mats of 512x64 fp32) -> Wt hi/lo bf16 [n=1536][k=512] ----
        const int idx = bid - 2048;
        const int mat = idx >> 3, k0 = (idx & 7) * 64;
#pragma unroll
        for (int c = 0; c < 4; ++c) {
            int id2 = t + c * 256;
            int kl = id2 >> 4, i4 = id2 & 15;
            float4 v = *(const float4*)&kern[((size_t)mat * 512 + k0 + kl) * 64 + i4 * 4];
            tile[(i4 * 4 + 0) * 65 + kl] = v.x;
            tile[(i4 * 4 + 1) * 65 + kl] = v.y;
            tile[(i4 * 4 + 2) * 65 + kl] = v.z;
            tile[(i4 * 4 + 3) * 65 + kl] = v.w;
        }
        __syncthreads();
        {
            int i = t >> 2, kq = t & 3;
            uint2 h0, l0, h1, l1, h2, l2, h3, l3;
            float f[16];
#pragma unroll
            for (int jj = 0; jj < 16; ++jj) f[jj] = tile[i * 65 + kq * 16 + jj];
            split4(f, h0, l0); split4(f + 4, h1, l1);
            split4(f + 8, h2, l2); split4(f + 12, h3, l3);
            size_t off = ((size_t)mat * 64 + i) * 512 + k0 + kq * 16;
            *(uint4*)&Wth[off]     = make_uint4(h0.x, h0.y, h1.x, h1.y);
            *(uint4*)&Wth[off + 8] = make_uint4(h2.x, h2.y, h3.x, h3.y);
            *(uint4*)&Wtl[off]     = make_uint4(l0.x, l0.y, l1.x, l1.y);
            *(uint4*)&Wtl[off + 8] = make_uint4(l2.x, l2.y, l3.x, l3.y);
        }
        return;
    }

    {
        // ---- HK (512x512 fp32) -> HKt hi/lo bf16 [n=512][k=512] (transpose) ----
        const int idx = bid - (2048 + 192);
        const int n0 = (idx >> 3) * 64, k0 = (idx & 7) * 64;
#pragma unroll
        for (int c = 0; c < 4; ++c) {
            int id2 = t + c * 256;
            int kl = id2 >> 4, n4 = id2 & 15;
            float4 v = *(const float4*)&HK[(size_t)(k0 + kl) * 512 + n0 + n4 * 4];
            tile[(n4 * 4 + 0) * 65 + kl] = v.x;
            tile[(n4 * 4 + 1) * 65 + kl] = v.y;
            tile[(n4 * 4 + 2) * 65 + kl] = v.z;
            tile[(n4 * 4 + 3) * 65 + kl] = v.w;
        }
        __syncthreads();
        {
            int i = t >> 2, kq = t & 3;
            uint2 h0, l0, h1, l1, h2, l2, h3, l3;
            float f[16];
#pragma unroll
            for (int jj = 0; jj < 16; ++jj) f[jj] = tile[i * 65 + kq * 16 + jj];
            split4(f, h0, l0); split4(f + 4, h1, l1);
            split4(f + 8, h2, l2); split4(f + 12, h3, l3);
            size_t off = (size_t)(n0 + i) * 512 + k0 + kq * 16;
            *(uint4*)&Hth[off]     = make_uint4(h0.x, h0.y, h1.x, h1.y);
            *(uint4*)&Hth[off + 8] = make_uint4(h2.x, h2.y, h3.x, h3.y);
            *(uint4*)&Htl[off]     = make_uint4(l0.x, l0.y, l1.x, l1.y);
            *(uint4*)&Htl[off + 8] = make_uint4(l2.x, l2.y, l3.x, l3.y);
        }
    }
}

// ---------------------------------------------------------------------------
// Kernel 1: QKV projection, split-bf16 MFMA (R14/R16-verified: spill-free,
// reg staging, waves_per_eu(3,3) -> 3 blocks/CU, 768-block grid in one round).
// ---------------------------------------------------------------------------
__global__ __launch_bounds__(256) __attribute__((amdgpu_waves_per_eu(3, 3)))
void qkv_mfma(const unsigned short* __restrict__ Xh,
              const unsigned short* __restrict__ Xl,
              const unsigned short* __restrict__ Wth,
              const unsigned short* __restrict__ Wtl,
              unsigned short* __restrict__ Qh,
              unsigned short* __restrict__ Ql,
              unsigned short* __restrict__ Kh,
              unsigned short* __restrict__ Kl,
              unsigned short* __restrict__ Vth,
              unsigned short* __restrict__ Vtl) {
    __shared__ __align__(16) unsigned short smem[16384];   // 32 KB
    unsigned short* Ah = smem;            // [m][k] 128x32
    unsigned short* Al = smem + 4096;
    unsigned short* Bh = smem + 8192;     // [n][k] 128x32
    unsigned short* Bl = smem + 12288;

    const int t = threadIdx.x;
    const int w = t >> 6, lane = t & 63;
    const int quad = lane >> 4, l16 = lane & 15;
    const int wm = w & 1, wn = w >> 1;
    const int r0 = blockIdx.x * 128, n0 = blockIdx.y * 128;

    floatx4 acc[4][4];
#pragma unroll
    for (int mt = 0; mt < 4; ++mt)
#pragma unroll
        for (int nt = 0; nt < 4; ++nt) acc[mt][nt] = (floatx4)(0.f);

    for (int ko = 0; ko < 16; ++ko) {
        const int k0 = ko * 32;
        __syncthreads();
#pragma unroll
        for (int c = 0; c < 2; ++c) {
            int idx = t + c * 256;            // 0..511: 128 rows x 4 parts
            int row = idx >> 2, part = idx & 3;
            size_t src = (size_t)(r0 + row) * 512 + k0 + part * 8;
            *(uint4*)&Ah[row * 32 + part * 8] = *(const uint4*)&Xh[src];
            *(uint4*)&Al[row * 32 + part * 8] = *(const uint4*)&Xl[src];
        }
#pragma unroll
        for (int c = 0; c < 2; ++c) {
            int idx = t + c * 256;
            int n = idx >> 2, part = idx & 3;
            size_t src = (size_t)(n0 + n) * 512 + k0 + part * 8;
            *(uint4*)&Bh[n * 32 + part * 8] = *(const uint4*)&Wth[src];
            *(uint4*)&Bl[n * 32 + part * 8] = *(const uint4*)&Wtl[src];
        }
        __syncthreads();

        short8 af[4], alf[4], bf[4], blf[4];
#pragma unroll
        for (int mt = 0; mt < 4; ++mt) {
            af[mt]  = *(const short8*)&Ah[(wm * 64 + mt * 16 + l16) * 32 + quad * 8];
            alf[mt] = *(const short8*)&Al[(wm * 64 + mt * 16 + l16) * 32 + quad * 8];
        }
#pragma unroll
        for (int nt = 0; nt < 4; ++nt) {
            bf[nt]  = *(const short8*)&Bh[(wn * 64 + nt * 16 + l16) * 32 + quad * 8];
            blf[nt] = *(const short8*)&Bl[(wn * 64 + nt * 16 + l16) * 32 + quad * 8];
        }
#pragma unroll
        for (int mt = 0; mt < 4; ++mt)
#pragma unroll
            for (int nt = 0; nt < 4; ++nt) {
                acc[mt][nt] = __builtin_amdgcn_mfma_f32_16x16x32_bf16(af[mt], bf[nt], acc[mt][nt], 0, 0, 0);
                acc[mt][nt] = __builtin_amdgcn_mfma_f32_16x16x32_bf16(af[mt], blf[nt], acc[mt][nt], 0, 0, 0);
                acc[mt][nt] = __builtin_amdgcn_mfma_f32_16x16x32_bf16(alf[mt], bf[nt], acc[mt][nt], 0, 0, 0);
            }
    }

    // Epilogue: wave-uniform mat, LDS repack, coalesced stores. Fully
    // unrolled (static acc indexing).
    __syncthreads();
    const int mat = (n0 + wn * 64) >> 6;
    const int h = mat / 3, j = mat - 3 * h;
    const size_t bh = (size_t)(r0 >> 11) * HEADS + h;
    float* pw = (float*)smem + w * 1088;    // 16 x 68 fp32 per wave
    // Q scale = (1/8) * log2(e): attn works in log2 domain -> exp2 = bare v_exp_f32
    const float scale = (j == 0) ? 0.18033688011112042f : 1.0f;

#pragma unroll
    for (int mt = 0; mt < 4; ++mt) {
        asm volatile("" ::: "memory");
#pragma unroll
        for (int nt = 0; nt < 4; ++nt)
#pragma unroll
            for (int r = 0; r < 4; ++r)
                pw[(quad * 4 + r) * 68 + nt * 16 + l16] = acc[mt][nt][r] * scale;
        asm volatile("s_waitcnt lgkmcnt(0)" ::: "memory");
        const int sbase = (r0 & 2047) + wm * 64 + mt * 16;
        if (j < 2) {
            unsigned short* dh = (j == 0) ? Qh : Kh;
            unsigned short* dl = (j == 0) ? Ql : Kl;
            float f[16];
            const float* pr = pw + l16 * 68 + quad * 16;
#pragma unroll
            for (int jj = 0; jj < 16; ++jj) f[jj] = pr[jj];
            uint2 h0, l0, h1, l1, h2, l2, h3, l3;
            split4(f, h0, l0); split4(f + 4, h1, l1);
            split4(f + 8, h2, l2); split4(f + 12, h3, l3);
            size_t off = (bh * SEQ + sbase + l16) * 64 + quad * 16;
            *(uint4*)&dh[off]     = make_uint4(h0.x, h0.y, h1.x, h1.y);
            *(uint4*)&dh[off + 8] = make_uint4(h2.x, h2.y, h3.x, h3.y);
            *(uint4*)&dl[off]     = make_uint4(l0.x, l0.y, l1.x, l1.y);
            *(uint4*)&dl[off + 8] = make_uint4(l2.x, l2.y, l3.x, l3.y);
        } else {
            float f[16];
#pragma unroll
            for (int ss = 0; ss < 16; ++ss) f[ss] = pw[ss * 68 + lane];
            uint2 h0, l0, h1, l1, h2, l2, h3, l3;
            split4(f, h0, l0); split4(f + 4, h1, l1);
            split4(f + 8, h2, l2); split4(f + 12, h3, l3);
            // permuted key layout within each 32-key block:
            //   key (16a + 4g + c) -> pos (8g + 4a + c);  f[4g+c] = key sbase+4g+c
            size_t bb = (bh * 64 + lane) * SEQ + (size_t)(sbase & ~31);
            const int a4 = (sbase & 16) ? 4 : 0;
            *(uint2*)&Vth[bb + a4]      = h0;
            *(uint2*)&Vth[bb + 8 + a4]  = h1;
            *(uint2*)&Vth[bb + 16 + a4] = h2;
            *(uint2*)&Vth[bb + 24 + a4] = h3;
            *(uint2*)&Vtl[bb + a4]      = l0;
            *(uint2*)&Vtl[bb + 8 + a4]  = l1;
            *(uint2*)&Vtl[bb + 16 + a4] = l2;
            *(uint2*)&Vtl[bb + 24 + a4] = l3;
        }
    }
}

// ---------------------------------------------------------------------------
// Kernel 2: flash attention — R16-verified (112 µs, MfmaUtil 40, spill-free).
// 512-thread blocks, 8 waves x 16 q, grid (32,16), waves_per_eu(4,4);
// in-register PV via key-permuted V, log2 softmax, defer-max THR=8.
// ---------------------------------------------------------------------------
__global__ __launch_bounds__(512) __attribute__((amdgpu_waves_per_eu(4, 4)))
void attn_mfma(
        const unsigned short* __restrict__ Qh_g, const unsigned short* __restrict__ Ql_g,
        const unsigned short* __restrict__ Kh_g, const unsigned short* __restrict__ Kl_g,
        const unsigned short* __restrict__ Vth_g, const unsigned short* __restrict__ Vtl_g,
        unsigned short* __restrict__ Oh_g, unsigned short* __restrict__ Ol_g) {
    __shared__ __align__(16) unsigned short smem[4 * 4608];   // 36,864 B
    unsigned short* Ksh = smem;                // [key][dim] 64x72
    unsigned short* Ksl = smem + 4608;
    unsigned short* Vsh = smem + 2 * 4608;     // [dim][pos] 64x72 (pos = permuted key)
    unsigned short* Vsl = smem + 3 * 4608;

    const int t = threadIdx.x;
    const int w = t >> 6, lane = t & 63;
    const int quad = lane >> 4, l16 = lane & 15;
    const int bh = blockIdx.x;
    const int qbase = blockIdx.y * 128 + w * 16;   // 16 queries per wave

    short8 qhf[2], qlf[2];
    {
        const unsigned short* p = Qh_g + ((size_t)bh * SEQ + qbase + l16) * INNER + quad * 8;
        qhf[0] = *(const short8*)p;
        qhf[1] = *(const short8*)(p + 32);
        const unsigned short* p2 = Ql_g + ((size_t)bh * SEQ + qbase + l16) * INNER + quad * 8;
        qlf[0] = *(const short8*)p2;
        qlf[1] = *(const short8*)(p2 + 32);
    }

    floatx4 o[4];
#pragma unroll
    for (int nt = 0; nt < 4; ++nt) o[nt] = (floatx4)(0.f);
    float mrun = -1e30f;
    float lrun = 0.f;

    const uint4* ksrc_h = (const uint4*)(Kh_g + (size_t)bh * SEQ * INNER);
    const uint4* ksrc_l = (const uint4*)(Kl_g + (size_t)bh * SEQ * INNER);
    const uint4* vsrc_h = (const uint4*)(Vth_g + (size_t)bh * INNER * SEQ);
    const uint4* vsrc_l = (const uint4*)(Vtl_g + (size_t)bh * INNER * SEQ);

    // staging geometry: 512 threads stage 512 uint4 per array (one each)
    const int srow = t >> 3, spart = t & 7;
    const int sdst = srow * 72 + spart * 8;

    // prefetch tile 0 into registers (one uint4 per array per thread)
    uint4 pkh, pkl, pvh, pvl;
    pkh = ksrc_h[t];
    pkl = ksrc_l[t];
    pvh = vsrc_h[srow * 256 + spart];
    pvl = vsrc_l[srow * 256 + spart];

    for (int kt = 0; kt < 32; ++kt) {
        __syncthreads();   // (A) prior tile's readers done; drains prefetch
        *(uint4*)&Ksh[sdst] = pkh;
        *(uint4*)&Ksl[sdst] = pkl;
        *(uint4*)&Vsh[sdst] = pvh;
        *(uint4*)&Vsl[sdst] = pvl;
        __syncthreads();   // (B) staging visible

        // ---- S^T: 4 subtiles of 16 keys (S in log2 units) ----
        floatx4 s[4];
        __builtin_amdgcn_s_setprio(1);
#pragma unroll
        for (int st = 0; st < 4; ++st) {
            const unsigned short* ka = &Ksh[(st * 16 + l16) * 72 + quad * 8];
            const unsigned short* kb = &Ksl[(st * 16 + l16) * 72 + quad * 8];
            short8 kh0 = *(const short8*)ka;
            short8 kh1 = *(const short8*)(ka + 32);
            short8 kl0 = *(const short8*)kb;
            short8 kl1 = *(const short8*)(kb + 32);
            floatx4 a = (floatx4)(0.f);
            a = __builtin_amdgcn_mfma_f32_16x16x32_bf16(kh0, qhf[0], a, 0, 0, 0);
            a = __builtin_amdgcn_mfma_f32_16x16x32_bf16(kh1, qhf[1], a, 0, 0, 0);
            a = __builtin_amdgcn_mfma_f32_16x16x32_bf16(kl0, qhf[0], a, 0, 0, 0);
            a = __builtin_amdgcn_mfma_f32_16x16x32_bf16(kl1, qhf[1], a, 0, 0, 0);
            a = __builtin_amdgcn_mfma_f32_16x16x32_bf16(kh0, qlf[0], a, 0, 0, 0);
            a = __builtin_amdgcn_mfma_f32_16x16x32_bf16(kh1, qlf[1], a, 0, 0, 0);
            s[st] = a;
        }
        __builtin_amdgcn_s_setprio(0);

        // ---- prefetch next tile (regs dead during QK^T; fly under PV) ----
        if (kt + 1 < 32) {
            pkh = ksrc_h[(kt + 1) * 512 + t];
            pkl = ksrc_l[(kt + 1) * 512 + t];
            pvh = vsrc_h[srow * 256 + (kt + 1) * 8 + spart];
            pvl = vsrc_l[srow * 256 + (kt + 1) * 8 + spart];
        }

        // ---- online softmax (log2 domain), defer-max THR=8 ----
        {
            float mloc = s[0][0];
#pragma unroll
            for (int st = 0; st < 4; ++st)
#pragma unroll
                for (int r = 0; r < 4; ++r) mloc = fmaxf(mloc, s[st][r]);
            mloc = fmaxf(mloc, __shfl_xor(mloc, 16));
            mloc = fmaxf(mloc, __shfl_xor(mloc, 32));
            if (!__all(mloc - mrun <= 8.f)) {
                float mn = fmaxf(mrun, mloc);
                float alpha = EXP2F(mrun - mn);
                mrun = mn;
                lrun *= alpha;
#pragma unroll
                for (int nt = 0; nt < 4; ++nt) o[nt] = o[nt] * alpha;
            }
            float rs = 0.f;
#pragma unroll
            for (int st = 0; st < 4; ++st)
#pragma unroll
                for (int r = 0; r < 4; ++r) {
                    float p = EXP2F(s[st][r] - mrun);
                    s[st][r] = p;
                    rs += p;
                }
            rs += __shfl_xor(rs, 16);
            rs += __shfl_xor(rs, 32);
            lrun += rs;
        }

        // ---- PV: P stays in registers.
        // B-operand slot (quad, j) wants key 32*half + 8*quad + j under the
        // permuted-V order, which equals s[2*half + (j>>2)][j&3] exactly. ----
#pragma unroll
        for (int half = 0; half < 2; ++half) {
            short8 phf, plf;
#pragma unroll
            for (int j = 0; j < 8; ++j) {
                unsigned short hu, lu;
                split_bf(s[2 * half + (j >> 2)][j & 3], hu, lu);
                phf[j] = (short)hu;
                plf[j] = (short)lu;
            }
            __builtin_amdgcn_s_setprio(1);
#pragma unroll
            for (int nt = 0; nt < 4; ++nt) {
                const unsigned short* va = &Vsh[(nt * 16 + l16) * 72 + half * 32 + quad * 8];
                const unsigned short* vb = &Vsl[(nt * 16 + l16) * 72 + half * 32 + quad * 8];
                short8 vh = *(const short8*)va;
                short8 vl = *(const short8*)vb;
                o[nt] = __builtin_amdgcn_mfma_f32_16x16x32_bf16(vh, phf, o[nt], 0, 0, 0);
                o[nt] = __builtin_amdgcn_mfma_f32_16x16x32_bf16(vh, plf, o[nt], 0, 0, 0);
                o[nt] = __builtin_amdgcn_mfma_f32_16x16x32_bf16(vl, phf, o[nt], 0, 0, 0);
            }
            __builtin_amdgcn_s_setprio(0);
        }
    }

    // ---- epilogue: repack O via LDS -> full-line coalesced uint4 stores.
    // Per-wave disjoint regions: 8 x 1088 fp32 = 34.8 KB within dead K/V smem.
    __syncthreads();   // all waves done reading K/V LDS; safe to reuse as scratch
    {
        const float inv = 1.f / lrun;
        float* pq = (float*)smem + w * 1088;
#pragma unroll
        for (int nt = 0; nt < 4; ++nt) {
            float4 v = make_float4(o[nt][0] * inv, o[nt][1] * inv,
                                   o[nt][2] * inv, o[nt][3] * inv);
            *(float4*)&pq[l16 * 68 + nt * 16 + quad * 4] = v;
        }
        asm volatile("s_waitcnt lgkmcnt(0)" ::: "memory");
        const float* pr = pq + l16 * 68 + quad * 16;
        float f[16];
#pragma unroll
        for (int jj = 0; jj < 16; ++jj) f[jj] = pr[jj];
        uint2 h0, l0, h1, l1, h2, l2, h3, l3;
        split4(f, h0, l0); split4(f + 4, h1, l1);
        split4(f + 8, h2, l2); split4(f + 12, h3, l3);
        size_t off = ((size_t)bh * SEQ + qbase + l16) * 64 + quad * 16;
        *(uint4*)&Oh_g[off]     = make_uint4(h0.x, h0.y, h1.x, h1.y);
        *(uint4*)&Oh_g[off + 8] = make_uint4(h2.x, h2.y, h3.x, h3.y);
        *(uint4*)&Ol_g[off]     = make_uint4(l0.x, l0.y, l1.x, l1.y);
        *(uint4*)&Ol_g[off + 8] = make_uint4(l2.x, l2.y, l3.x, l3.y);
    }
}

// ---------------------------------------------------------------------------
// Kernel 3: output projection, split-bf16 MFMA. 64x128 tiles, grid (128,4)
// = 512 blocks = exactly 2 blocks/CU; waves_per_eu(2,2) (R14/R16-verified,
// reg staging).
// ---------------------------------------------------------------------------
__global__ __launch_bounds__(256) __attribute__((amdgpu_waves_per_eu(2, 2)))
void out_proj_mfma(const unsigned short* __restrict__ Oh,
                   const unsigned short* __restrict__ Ol,
                   const unsigned short* __restrict__ Hth,
                   const unsigned short* __restrict__ Htl,
                   float* __restrict__ Y) {
    __shared__ __align__(16) unsigned short smem[12288];   // 24.6 KB
    unsigned short* Ah = smem;            // 64 x 32
    unsigned short* Al = smem + 2048;
    unsigned short* Bh = smem + 4096;     // 128 x 32
    unsigned short* Bl = smem + 8192;

    const int t = threadIdx.x;
    const int w = t >> 6, lane = t & 63;
    const int quad = lane >> 4, l16 = lane & 15;
    const int wm = w & 1, wn = w >> 1;
    const int r0 = blockIdx.x * 64, n0 = blockIdx.y * 128;
    const int b = r0 >> 11;

    floatx4 acc[2][4];
#pragma unroll
    for (int mt = 0; mt < 2; ++mt)
#pragma unroll
        for (int nt = 0; nt < 4; ++nt) acc[mt][nt] = (floatx4)(0.f);

    for (int ko = 0; ko < 16; ++ko) {
        const int h = ko >> 1, d0 = (ko & 1) * 32;
        const size_t bh = (size_t)b * HEADS + h;
        const int k0 = ko * 32;
        __syncthreads();
        {
            int row = t >> 2, part = t & 3;   // 64 rows x 4 parts = 256
            size_t src = (bh * SEQ + (r0 & 2047) + row) * 64 + d0 + part * 8;
            *(uint4*)&Ah[row * 32 + part * 8] = *(const uint4*)&Oh[src];
            *(uint4*)&Al[row * 32 + part * 8] = *(const uint4*)&Ol[src];
        }
#pragma unroll
        for (int c = 0; c < 2; ++c) {
            int idx = t + c * 256;            // 128 cols x 4 parts = 512
            int n = idx >> 2, part = idx & 3;
            size_t src = (size_t)(n0 + n) * 512 + k0 + part * 8;
            *(uint4*)&Bh[n * 32 + part * 8] = *(const uint4*)&Hth[src];
            *(uint4*)&Bl[n * 32 + part * 8] = *(const uint4*)&Htl[src];
        }
        __syncthreads();

        short8 af[2], alf[2], bf[4], blf[4];
#pragma unroll
        for (int mt = 0; mt < 2; ++mt) {
            af[mt]  = *(const short8*)&Ah[(wm * 32 + mt * 16 + l16) * 32 + quad * 8];
            alf[mt] = *(const short8*)&Al[(wm * 32 + mt * 16 + l16) * 32 + quad * 8];
        }
#pragma unroll
        for (int nt = 0; nt < 4; ++nt) {
            bf[nt]  = *(const short8*)&Bh[(wn * 64 + nt * 16 + l16) * 32 + quad * 8];
            blf[nt] = *(const short8*)&Bl[(wn * 64 + nt * 16 + l16) * 32 + quad * 8];
        }
#pragma unroll
        for (int mt = 0; mt < 2; ++mt)
#pragma unroll
            for (int nt = 0; nt < 4; ++nt) {
                acc[mt][nt] = __builtin_amdgcn_mfma_f32_16x16x32_bf16(af[mt], bf[nt], acc[mt][nt], 0, 0, 0);
                acc[mt][nt] = __builtin_amdgcn_mfma_f32_16x16x32_bf16(af[mt], blf[nt], acc[mt][nt], 0, 0, 0);
                acc[mt][nt] = __builtin_amdgcn_mfma_f32_16x16x32_bf16(alf[mt], bf[nt], acc[mt][nt], 0, 0, 0);
            }
    }

#pragma unroll
    for (int mt = 0; mt < 2; ++mt)
#pragma unroll
        for (int nt = 0; nt < 4; ++nt)
#pragma unroll
            for (int r = 0; r < 4; ++r)
                Y[(size_t)(r0 + wm * 32 + mt * 16 + quad * 4 + r) * 512 +
                  n0 + wn * 64 + nt * 16 + l16] = acc[mt][nt][r];
}

extern "C" void kernel_launch(void* const* d_in, const int* in_sizes, int n_in,
                              void* d_out, int out_size, void* d_ws, size_t ws_size,
                              hipStream_t stream) {
    const float* x    = (const float*)d_in[0];
    const float* kern = (const float*)d_in[1];
    const float* hk   = (const float*)d_in[2];
    float* y = (float*)d_out;

    unsigned short* Qh  = (unsigned short*)d_ws;
    unsigned short* Ql  = Qh + PER_MAT;
    unsigned short* Kh  = Qh + 2 * PER_MAT;
    unsigned short* Kl  = Qh + 3 * PER_MAT;
    unsigned short* Vth = Qh + 4 * PER_MAT;
    unsigned short* Vtl = Qh + 5 * PER_MAT;
    // Xh/Xl alias Oh/Ol: X is dead by the time attn writes O (stream order)
    unsigned short* Oh  = Qh + 6 * PER_MAT;
    unsigned short* Ol  = Qh + 7 * PER_MAT;
    unsigned short* Xh  = Oh;
    unsigned short* Xl  = Ol;
    unsigned short* Wth = Qh + 8 * PER_MAT;
    unsigned short* Wtl = Wth + (size_t)1536 * 512;
    unsigned short* Hth = Wtl + (size_t)1536 * 512;
    unsigned short* Htl = Hth + (size_t)512 * 512;

    split_all<<<dim3(2304), 256, 0, stream>>>(x, Xh, Xl, kern, Wth, Wtl, hk, Hth, Htl);
    qkv_mfma<<<dim3(64, 12), 256, 0, stream>>>(Xh, Xl, Wth, Wtl, Qh, Ql, Kh, Kl, Vth, Vtl);
    attn_mfma<<<dim3(32, 16), 512, 0, stream>>>(Qh, Ql, Kh, Kl, Vth, Vtl, Oh, Ol);
    out_proj_mfma<<<dim3(128, 4), 256, 0, stream>>>(Oh, Ol, Hth, Htl, y);
}